// Round 8
// baseline (33103.949 us; speedup 1.0000x reference)
//
#include <hip/hip_runtime.h>
#include <math.h>

#define BB 32
#define SS 64
#define HH 256
#define NT 512

// ws float offsets
//  [0]        enc half-packs: 4 mats x 2 halves x 512rows x 64kq x4 = 1,048,576 f
//  [1048576]  dec full-packs: 4 mats x 1024rows x 64kq x4 = 1,048,576 f
//  W1T_OFF    W1T k-major 256x256; W2T_OFF likewise
//  PB_OFF     per-batch: X1h[2][64][512], h1cw[64][256], p2h[2][16][512],
//             h2cw[64][256], dc1i[256], dc2i[256], embw[256]
//  FLG_OFF    per-batch 8 flag lines x 32 words (each flag own 128B line); abort after
#define W1T_OFF 2097152
#define W2T_OFF 2162688
#define PB_OFF  2228224
#define PBB     115712
#define OX1     0
#define OH1     65536
#define OP2     81920
#define OH2     98304
#define ODC1    114688
#define ODC2    114944
#define OEMB    115200
#define FLG_OFF (PB_OFF + 32*PBB)
#define FA0 0
#define FA1 32
#define FB0 64
#define FB1 96
#define FC0 128
#define FC1 160
#define FD  192
#define NFLGW (32*256 + 32)

__device__ __forceinline__ float sigmf(float x){ return 1.f/(1.f+expf(-x)); }
__device__ __forceinline__ float dot4(float4 a, float4 b){
  return fmaf(a.x,b.x,fmaf(a.y,b.y,fmaf(a.z,b.z,a.w*b.w)));
}
// Relaxed agent-scope transport (R7-proven: LLC-coherent anywhere, no L2-inval storms).
// Ordering: payload srel -> drain_vm -> barrier -> flag fst.
__device__ __forceinline__ void fst(unsigned* p, unsigned v){
  __hip_atomic_store(p, v, __ATOMIC_RELAXED, __HIP_MEMORY_SCOPE_AGENT);
}
__device__ __forceinline__ unsigned fld(unsigned* p){
  return __hip_atomic_load(p, __ATOMIC_RELAXED, __HIP_MEMORY_SCOPE_AGENT);
}
__device__ __forceinline__ void srel(float* p, float v){
  __hip_atomic_store(p, v, __ATOMIC_RELAXED, __HIP_MEMORY_SCOPE_AGENT);
}
__device__ __forceinline__ float lrel(const float* p){
  return __hip_atomic_load((float*)p, __ATOMIC_RELAXED, __HIP_MEMORY_SCOPE_AGENT);
}
__device__ __forceinline__ void drain_vm(){
  asm volatile("s_waitcnt vmcnt(0)" ::: "memory");
}
__device__ __forceinline__ int wait_ge(unsigned* p, unsigned want, unsigned* ab){
  int it = 0;
  for(;;){
    unsigned v = fld(p);
    if (v >= want) return (int)v;
    if ((++it & 2047) == 0){
      if (fld(ab) != 0u) return -1;
      if (it > (1<<23)){ fst(ab, 1u); return -1; }
    }
    __builtin_amdgcn_s_sleep(1);
  }
}

__global__ void zflags_k(float* ws){
  unsigned* f = (unsigned*)(ws + FLG_OFF);
  int i = blockIdx.x*1024 + threadIdx.x;
  if (i < NFLGW) f[i] = 0u;
}

// Pack: enc half-packs dst4[(m*2+x)*32768 + kq*512 + r] = src[grow*256+kq*4 ..],
//   grow = (r>>7)*256 + x*128 + (r&127)   (r = gate*128 + jloc)
// dec full-packs dst4[262144 + m*65536 + kq*1024 + row] = src[row*256+kq*4 ..]
__global__ void pack_k(const float* __restrict__ e0ih, const float* __restrict__ e0hh,
                       const float* __restrict__ e1ih, const float* __restrict__ e1hh,
                       const float* __restrict__ d0ih, const float* __restrict__ d0hh,
                       const float* __restrict__ d1ih, const float* __restrict__ d1hh,
                       float* __restrict__ ws){
  const float* encm[4] = {e0ih,e0hh,e1ih,e1hh};
  const float* decm[4] = {d0ih,d0hh,d1ih,d1hh};
  float4* dst = (float4*)ws;
  int gid = blockIdx.x*256 + threadIdx.x;
  if (gid < 262144){
    int mx = gid >> 15, rem = gid & 32767;
    int kq = rem >> 9, r = rem & 511;
    int m = mx >> 1, x = mx & 1;
    int grow = ((r>>7)<<8) + (x<<7) + (r&127);
    dst[gid] = *(const float4*)&encm[m][(size_t)grow*256 + kq*4];
  } else {
    int g2 = gid - 262144;
    int m = g2 >> 16, rem = g2 & 65535;
    int kq = rem >> 10, row = rem & 1023;
    dst[gid] = *(const float4*)&decm[m][(size_t)row*256 + kq*4];
  }
}

// dst[k*256+j] = src[j*256+k]
__global__ void transpose256_k(const float* __restrict__ W1, const float* __restrict__ W2,
                               float* __restrict__ ws) {
  __shared__ float tile[32][33];
  const float* src = blockIdx.z ? W2 : W1;
  float* dst = ws + (blockIdx.z ? W2T_OFF : W1T_OFF);
  int j0 = blockIdx.x * 32, k0 = blockIdx.y * 32;
  int tx = threadIdx.x & 31, ty = threadIdx.x >> 5;
  for (int i = ty; i < 32; i += 8) tile[i][tx] = src[(size_t)(j0 + i) * HH + k0 + tx];
  __syncthreads();
  for (int i = ty; i < 32; i += 8) dst[(size_t)(k0 + i) * HH + j0 + tx] = tile[tx][i];
}

__global__ void __launch_bounds__(NT) ptrnet_k(
    const float* __restrict__ inputs, const float* __restrict__ W_emb,
    const float* __restrict__ b_emb,
    const float* __restrict__ b_e0, const float* __restrict__ b_e1,
    const float* __restrict__ b_d0, const float* __restrict__ b_d1,
    const float* __restrict__ vv,
    float* __restrict__ ws, float* __restrict__ out) {
  const int g = blockIdx.x;
  const int role = g & 7;   // 0:A0 1:A1 2:B0 3:B1 4:C0 5:C1 6:D 7:spare
  const int b = g >> 3;
  const int tid = threadIdx.x;
  if (role == 7) return;

  const float4* ws4 = (const float4*)ws;
  const float* W1T = ws + W1T_OFF;
  const float* W2T = ws + W2T_OFF;

  float* pb   = ws + PB_OFF + (size_t)b * PBB;
  float* h1cw = pb + OH1;
  float* h2cw = pb + OH2;
  float* dc1i = pb + ODC1;
  float* dc2i = pb + ODC2;
  float* embw = pb + OEMB;
  unsigned* W = (unsigned*)(ws + FLG_OFF);
  unsigned* flg = W + b*256;
  unsigned* abw = W + 32*256;

  __shared__ float big0[16384];
  __shared__ float big1[16384];
  __shared__ float gb2[2048];
  __shared__ float gbuf[512];
  __shared__ __align__(16) float vA[128], vB[128];
  __shared__ __align__(16) float v0[256], v1[256], v2[256], v3[256], v4[256], v5[256], v6[256];
  __shared__ float scr[64];
  __shared__ int msk[64];
  __shared__ int ibc[2];

  // ============== roles A0/A1: layer-1 recurrence, half x ==============
  if (role < 2) {
    const int x = role, px = 1 - x;
    const float4* Wih = ws4 + (0*2 + x)*32768;   // e0ih half
    const float4* Whh = ws4 + (1*2 + x)*32768;   // e0hh half
    float* X1x = pb + OX1 + x*32768;             // [64][512]
    const int r = tid;
    const int grow = ((r>>7)<<8) + (x<<7) + (r&127);
    const float be0r = b_e0[grow];
    unsigned* myF = &flg[x ? FA1 : FA0];
    unsigned* peF = &flg[x ? FA0 : FA1];

    // preE into big0
    for (int i = tid; i < SS*HH; i += NT){
      int t = i >> 8, j = i & 255;
      const float* xr = inputs + ((size_t)b*SS + t)*8;
      float acc = b_emb[j];
#pragma unroll
      for (int d = 0; d < 8; ++d) acc = fmaf(xr[d], W_emb[j*8+d], acc);
      big0[i] = acc;
    }
    __syncthreads();
    // X1 init: 8 tiles of 8 t
    for (int tile = 0; tile < 8; ++tile){
      for (int i = tid; i < 2048; i += NT){
        int tt = i >> 8, j = i & 255;
        gb2[i] = tanhf(big0[(tile*8+tt)*256 + j]);
      }
      __syncthreads();
      float a[8] = {0,0,0,0,0,0,0,0};
      for (int kq = 0; kq < 64; ++kq){
        float4 w = Wih[(kq<<9) + r];
#pragma unroll
        for (int tt = 0; tt < 8; ++tt) a[tt] += dot4(w, *(const float4*)&gb2[tt*256 + kq*4]);
      }
#pragma unroll
      for (int tt = 0; tt < 8; ++tt) X1x[(tile*8+tt)*512 + r] = be0r + a[tt];
      __syncthreads();
    }
    // big0 is now c1c (own half): big0[t*128 + jloc]
    int tau = 0;
    for (int p = 0; p < SS; ++p){
      int t0 = 0;
      float x1t0 = 0.f; bool fuse = false;
      if (p > 0){
        if (tid == 0){
          int iv = wait_ge(&flg[FD], (unsigned)p << 8, abw);
          ibc[0] = (iv < 0) ? 0 : (iv & 255);
        }
        __syncthreads();
        t0 = ibc[0];
        if (tid < 256) v1[tid] = lrel(&embw[tid]);
        __syncthreads();
        float accR = be0r;
        for (int kq = 0; kq < 64; ++kq)
          accR += dot4(Wih[(kq<<9) + r], *(const float4*)&v1[kq*4]);
        X1x[t0*512 + r] = accR;
        x1t0 = accR; fuse = true;
      }
      for (int t = t0; t < SS; ++t){
        ++tau;
        if (t == t0){
          if (tid < 128){
            float a0 = 0.f, b0 = 0.f;
            if (t0 > 0){
              a0 = lrel(&h1cw[(t0-1)*256 + x*128 + tid]);
              b0 = lrel(&h1cw[(t0-1)*256 + px*128 + tid]);
            }
            vA[tid] = a0; vB[tid] = b0;
          }
          __syncthreads();
        }
        float acc = (fuse && t == t0) ? x1t0 : X1x[t*512 + r];
        for (int kq = x*32; kq < x*32+32; ++kq)
          acc += dot4(Whh[(kq<<9) + r], *(const float4*)&vA[(kq - x*32)*4]);
        if (t > t0){
          if (tid == 0) wait_ge(peF, (unsigned)(tau-1), abw);
          __syncthreads();
          if (tid < 128) vB[tid] = lrel(&h1cw[(t-1)*256 + px*128 + tid]);
          __syncthreads();
        }
        for (int kq = px*32; kq < px*32+32; ++kq)
          acc += dot4(Whh[(kq<<9) + r], *(const float4*)&vB[(kq - px*32)*4]);
        gbuf[r] = acc;
        __syncthreads();
        if (tid < 128){
          float Gi = gbuf[tid], Gf = gbuf[128+tid], Gg = gbuf[256+tid], Go = gbuf[384+tid];
          float cp = (t == 0) ? 0.f : big0[(t-1)*128 + tid];
          float cc = sigmf(Gf)*cp + sigmf(Gi)*tanhf(Gg);
          float hh = sigmf(Go)*tanhf(cc);
          big0[t*128 + tid] = cc; vA[tid] = hh;
          srel(&h1cw[t*256 + x*128 + tid], hh);
          if (p == 0 && t == SS-1) srel(&dc1i[x*128 + tid], cc);
        }
        drain_vm();
        __syncthreads();
        if (tid == 0) fst(myF, (unsigned)tau);
      }
    }
  }
  // ============== roles B0/B1: p2 half = b_e1 + Wih1h . h1(t) ==============
  else if (role < 4) {
    const int x = role - 2;
    const float4* Wih1 = ws4 + (2*2 + x)*32768;
    float* p2x = pb + OP2 + x*8192;    // [16][512]
    const int r = tid;
    const float be1r = b_e1[((r>>7)<<8) + (x<<7) + (r&127)];
    unsigned* fC = &flg[x ? FC1 : FC0];
    unsigned* fB = &flg[x ? FB1 : FB0];
    int tau = 0;
    for (int p = 0; p < SS; ++p){
      int t0 = 0;
      if (p > 0){
        if (tid == 0){
          int iv = wait_ge(&flg[FD], (unsigned)p << 8, abw);
          ibc[0] = (iv < 0) ? 0 : (iv & 255);
        }
        __syncthreads();
        t0 = ibc[0];
      }
      for (int t = t0; t < SS; ++t){
        ++tau;
        if (tid == 0){
          wait_ge(&flg[FA0], (unsigned)tau, abw);
          wait_ge(&flg[FA1], (unsigned)tau, abw);
          if (tau > 16) wait_ge(fC, (unsigned)(tau-16), abw);
        }
        __syncthreads();
        if (tid < 256) v0[tid] = lrel(&h1cw[t*256 + tid]);
        __syncthreads();
        float acc = be1r;
        for (int kq = 0; kq < 64; ++kq)
          acc += dot4(Wih1[(kq<<9) + r], *(const float4*)&v0[kq*4]);
        srel(&p2x[(tau & 15)*512 + r], acc);
        drain_vm();
        __syncthreads();
        if (tid == 0) fst(fB, (unsigned)tau);
      }
    }
  }
  // ============== roles C0/C1: layer-2 recurrence, half x ==============
  else if (role < 6) {
    const int x = role - 4, px = 1 - x;
    const float4* Whh1 = ws4 + (3*2 + x)*32768;
    float* p2x = pb + OP2 + x*8192;
    const int r = tid;
    unsigned* myF = &flg[x ? FC1 : FC0];
    unsigned* peF = &flg[x ? FC0 : FC1];
    unsigned* fB = &flg[x ? FB1 : FB0];
    int tau = 0;
    for (int p = 0; p < SS; ++p){
      int t0 = 0;
      if (p > 0){
        if (tid == 0){
          int iv = wait_ge(&flg[FD], (unsigned)p << 8, abw);
          ibc[0] = (iv < 0) ? 0 : (iv & 255);
        }
        __syncthreads();
        t0 = ibc[0];
      }
      for (int t = t0; t < SS; ++t){
        ++tau;
        if (t == t0){
          if (tid < 128){
            float a0 = 0.f, b0 = 0.f;
            if (t0 > 0){
              a0 = lrel(&h2cw[(t0-1)*256 + x*128 + tid]);
              b0 = lrel(&h2cw[(t0-1)*256 + px*128 + tid]);
            }
            vA[tid] = a0; vB[tid] = b0;
          }
          __syncthreads();
        }
        float acc = 0.f;
        for (int kq = x*32; kq < x*32+32; ++kq)
          acc += dot4(Whh1[(kq<<9) + r], *(const float4*)&vA[(kq - x*32)*4]);
        if (tid == 0){
          wait_ge(fB, (unsigned)tau, abw);
          if (t > t0) wait_ge(peF, (unsigned)(tau-1), abw);
        }
        __syncthreads();
        if (t > t0){
          if (tid < 128) vB[tid] = lrel(&h2cw[(t-1)*256 + px*128 + tid]);
        }
        float p2v = lrel(&p2x[(tau & 15)*512 + r]);
        __syncthreads();
        for (int kq = px*32; kq < px*32+32; ++kq)
          acc += dot4(Whh1[(kq<<9) + r], *(const float4*)&vB[(kq - px*32)*4]);
        gbuf[r] = acc + p2v;
        __syncthreads();
        if (tid < 128){
          float Gi = gbuf[tid], Gf = gbuf[128+tid], Gg = gbuf[256+tid], Go = gbuf[384+tid];
          float cp = (t == 0) ? 0.f : big0[(t-1)*128 + tid];   // c2c own half
          float cc = sigmf(Gf)*cp + sigmf(Gi)*tanhf(Gg);
          float hh = sigmf(Go)*tanhf(cc);
          big0[t*128 + tid] = cc; vA[tid] = hh;
          srel(&h2cw[t*256 + x*128 + tid], hh);
          if (p == 0 && t == SS-1) srel(&dc2i[x*128 + tid], cc);
        }
        drain_vm();
        __syncthreads();
        if (tid == 0) fst(myF, (unsigned)tau);
      }
    }
  }
  // ============== role D: eW1, decoder cell, attention, argmax ==============
  else {
    const float4* WD0ih = ws4 + 262144 + 0*65536;
    const float4* WD0hh = ws4 + 262144 + 1*65536;
    const float4* WD1ih = ws4 + 262144 + 2*65536;
    const float4* WD1hh = ws4 + 262144 + 3*65536;
    for (int i = tid; i < SS*HH; i += NT){
      int t = i >> 8, j = i & 255;
      const float* xr = inputs + ((size_t)b*SS + t)*8;
      float acc = b_emb[j];
#pragma unroll
      for (int d = 0; d < 8; ++d) acc = fmaf(xr[d], W_emb[j*8+d], acc);
      big0[i] = acc;  // preE, kept whole run
    }
    if (tid < 64) msk[tid] = 0;
    __syncthreads();

    // v2=dins v3=dh1 v4=dc1 v5=dh2 v6=dc2 v1=a2
    auto dec_cell = [&](){
#pragma unroll
      for (int h = 0; h < 2; ++h){
        int row = h*512 + tid;
        float acc = b_d0[row];
        for (int kq = 0; kq < 64; ++kq){
          acc += dot4(WD0ih[(kq<<10) + row], *(const float4*)&v2[kq*4]);
          acc += dot4(WD0hh[(kq<<10) + row], *(const float4*)&v3[kq*4]);
        }
        gb2[row] = acc;
      }
      __syncthreads();
      if (tid < 256){
        float Gi = gb2[tid], Gf = gb2[256+tid], Gg = gb2[512+tid], Go = gb2[768+tid];
        float cc = sigmf(Gf)*v4[tid] + sigmf(Gi)*tanhf(Gg);
        float hh = sigmf(Go)*tanhf(cc);
        v4[tid] = cc; v3[tid] = hh;
      }
      __syncthreads();
#pragma unroll
      for (int h = 0; h < 2; ++h){
        int row = h*512 + tid;
        float acc = b_d1[row];
        for (int kq = 0; kq < 64; ++kq){
          acc += dot4(WD1ih[(kq<<10) + row], *(const float4*)&v3[kq*4]);
          acc += dot4(WD1hh[(kq<<10) + row], *(const float4*)&v5[kq*4]);
        }
        gb2[row] = acc;
      }
      __syncthreads();
      if (tid < 256){
        float Gi = gb2[tid], Gf = gb2[256+tid], Gg = gb2[512+tid], Go = gb2[768+tid];
        float cc = sigmf(Gf)*v6[tid] + sigmf(Gi)*tanhf(Gg);
        float hh = sigmf(Go)*tanhf(cc);
        v6[tid] = cc; v5[tid] = hh;
      }
      __syncthreads();
      { int j = tid & 255, c = tid >> 8;   // a2 = dh2 @ W2^T, 2-way k-split
        float a = 0.f;
        for (int k = c*128; k < c*128 + 128; ++k) a = fmaf(v5[k], W2T[k*256 + j], a);
        gbuf[tid] = a; }
      __syncthreads();
      if (tid < 256) v1[tid] = gbuf[tid] + gbuf[256+tid];
      __syncthreads();
    };

    int tau = 0, lastidx = 0;
    for (int p = 0; p < SS; ++p){
      int t0 = (p == 0) ? 0 : lastidx;
      if (p > 0) dec_cell();   // overlaps with upstream re-encode
      for (int t = t0; t < SS; ++t){
        ++tau;
        if (tid == 0){
          wait_ge(&flg[FC0], (unsigned)tau, abw);
          wait_ge(&flg[FC1], (unsigned)tau, abw);
        }
        __syncthreads();
        if (tid < 256) v0[tid] = lrel(&h2cw[t*256 + tid]);
        __syncthreads();
        { int j = tid & 255, c = tid >> 8;   // eW1 row t, 2-way k-split
          float a = 0.f;
          for (int k = c*128; k < c*128 + 128; ++k) a = fmaf(v0[k], W1T[k*256 + j], a);
          gbuf[tid] = a; }
        __syncthreads();
        if (tid < 256) big1[t*256 + tid] = gbuf[tid] + gbuf[256+tid];
        __syncthreads();
      }
      if (p == 0){
        if (tid < 256){
          v3[tid] = lrel(&h1cw[63*256 + tid]);
          v4[tid] = lrel(&dc1i[tid]);
          v5[tid] = lrel(&h2cw[63*256 + tid]);
          v6[tid] = lrel(&dc2i[tid]);
          v2[tid] = lrel(&h2cw[0*256 + tid]);
        }
        __syncthreads();
        dec_cell();
      }
      // scores: 8 lanes per t
      { int t = tid >> 3, r8 = tid & 7;
        float a = 0.f;
        for (int j = r8; j < HH; j += 8) a += vv[j] * tanhf(big1[t*256 + j] + v1[j]);
        a += __shfl_xor(a, 4, 8);
        a += __shfl_xor(a, 2, 8);
        a += __shfl_xor(a, 1, 8);
        if (r8 == 0) scr[t] = msk[t] ? -3.0e38f : a; }
      __syncthreads();
      if (tid < SS){
        float sv = scr[tid];
        float m = sv; int mi = tid;
#pragma unroll
        for (int o = 32; o >= 1; o >>= 1){
          float ov = __shfl_xor(m, o, 64);
          int oi = __shfl_xor(mi, o, 64);
          if (ov > m || (ov == m && oi < mi)){ m = ov; mi = oi; }
        }
        float e = expf(sv - m);
        float ssum = e;
#pragma unroll
        for (int o = 32; o >= 1; o >>= 1) ssum += __shfl_xor(ssum, o, 64);
        out[((size_t)b*SS + p)*SS + tid] = e / ssum;
        if (tid == 0){
          msk[mi] = 1;
          out[(size_t)BB*SS*SS + (size_t)b*SS + p] = (float)mi;
          ibc[1] = mi;
        }
      }
      __syncthreads();
      int idx = ibc[1];
      lastidx = idx;
      if (p < SS-1){
        if (tid < 256){
          v2[tid] = lrel(&h2cw[idx*256 + tid]);   // dins, read BEFORE publish
          float e = tanhf(big0[idx*256 + tid] + W_emb[tid*8 + 7]);
          srel(&embw[tid], e);
        }
        drain_vm();
        __syncthreads();
        if (tid == 0) fst(&flg[FD], ((unsigned)(p+1) << 8) | (unsigned)idx);
      }
    }
  }
}

extern "C" void kernel_launch(void* const* d_in, const int* in_sizes, int n_in,
                              void* d_out, int out_size, void* d_ws, size_t ws_size,
                              hipStream_t stream) {
  const float* inputs = (const float*)d_in[0];
  const float* W_emb  = (const float*)d_in[1];
  const float* b_emb  = (const float*)d_in[2];
  const float* e_Wih0 = (const float*)d_in[3];
  const float* e_Whh0 = (const float*)d_in[4];
  const float* e_b0   = (const float*)d_in[5];
  const float* e_Wih1 = (const float*)d_in[6];
  const float* e_Whh1 = (const float*)d_in[7];
  const float* e_b1   = (const float*)d_in[8];
  const float* d_Wih0 = (const float*)d_in[9];
  const float* d_Whh0 = (const float*)d_in[10];
  const float* d_b0   = (const float*)d_in[11];
  const float* d_Wih1 = (const float*)d_in[12];
  const float* d_Whh1 = (const float*)d_in[13];
  const float* d_b1   = (const float*)d_in[14];
  const float* W1     = (const float*)d_in[15];
  const float* W2     = (const float*)d_in[16];
  const float* v      = (const float*)d_in[17];
  float* ws  = (float*)d_ws;
  float* out = (float*)d_out;

  zflags_k<<<dim3(9), dim3(1024), 0, stream>>>(ws);
  pack_k<<<dim3(2048), dim3(256), 0, stream>>>(
      e_Wih0, e_Whh0, e_Wih1, e_Whh1, d_Wih0, d_Whh0, d_Wih1, d_Whh1, ws);
  transpose256_k<<<dim3(8, 8, 2), dim3(256), 0, stream>>>(W1, W2, ws);
  ptrnet_k<<<dim3(BB*8), dim3(NT), 0, stream>>>(
      inputs, W_emb, b_emb, e_b0, e_b1, d_b0, d_b1, v, ws, out);
}

// Round 9
// 22080.215 us; speedup vs baseline: 1.4993x; 1.4993x over previous
//
#include <hip/hip_runtime.h>
#include <math.h>

#define BB 32
#define SS 64
#define HH 256
#define G4 1024
#define NT 1024

// ws float offsets
//  [0]        8 gate mats packed k-major f4 (R2 format), 262144 floats each
//  W1T_OFF    W1T k-major 256x256; W2T_OFF likewise
//  PB_OFF     per-batch: X1[64][1024], h1cw[64][256], p2 ring[16][1024],
//             h2cw[64][256], dc1i[256], dc2i[256], (embw unused)
//  FLG_OFF    per-batch 8 padded flag lines (32 words each); abort line at +8192
//  X1B_OFF    optional per-batch X1alt[64][1024] (guarded by ws_size)
#define W1T_OFF 2097152
#define W2T_OFF 2162688
#define PB_OFF  2228224
#define PBB     115712
#define OX1     0
#define OH1     65536
#define OP2     81920
#define OH2     98304
#define ODC1    114688
#define ODC2    114944
#define FLG_OFF (PB_OFF + 32*PBB)
#define NFLGW   (32*256 + 32)
#define X1B_OFF (FLG_OFF + NFLGW)
#define FA 0
#define FB 32
#define FC 64
#define FD 96

__device__ __forceinline__ float sigmf(float x){ return 1.f/(1.f+expf(-x)); }
__device__ __forceinline__ float dot4(float4 a, float4 b){
  return fmaf(a.x,b.x,fmaf(a.y,b.y,fmaf(a.z,b.z,a.w*b.w)));
}
// Relaxed agent-scope transport (R7-proven). Ordering: payload srel ->
// drain_vm -> barrier -> flag fst. One-directional waits only.
__device__ __forceinline__ void fst(unsigned* p, unsigned v){
  __hip_atomic_store(p, v, __ATOMIC_RELAXED, __HIP_MEMORY_SCOPE_AGENT);
}
__device__ __forceinline__ unsigned fld(unsigned* p){
  return __hip_atomic_load(p, __ATOMIC_RELAXED, __HIP_MEMORY_SCOPE_AGENT);
}
__device__ __forceinline__ void srel(float* p, float v){
  __hip_atomic_store(p, v, __ATOMIC_RELAXED, __HIP_MEMORY_SCOPE_AGENT);
}
__device__ __forceinline__ float lrel(const float* p){
  return __hip_atomic_load((float*)p, __ATOMIC_RELAXED, __HIP_MEMORY_SCOPE_AGENT);
}
__device__ __forceinline__ void drain_vm(){
  asm volatile("s_waitcnt vmcnt(0)" ::: "memory");
}
__device__ __forceinline__ int wait_ge(unsigned* p, unsigned want, unsigned* ab){
  int it = 0;
  for(;;){
    unsigned v = fld(p);
    if (v >= want) return (int)v;
    if ((++it & 2047) == 0){
      if (fld(ab) != 0u) return -1;
      if (it > (1<<23)){ fst(ab, 1u); return -1; }
    }
    __builtin_amdgcn_s_sleep(2);
  }
}

__global__ void zflags_k(float* ws){
  unsigned* f = (unsigned*)(ws + FLG_OFF);
  int i = blockIdx.x*1024 + threadIdx.x;
  if (i < NFLGW) f[i] = 0u;
}

// R2-validated pack: dst[((k>>2)*1024 + g)*4 + (k&3)] = src[g*256 + k]
__global__ void pack_transpose_k(const float* __restrict__ s0, const float* __restrict__ s1,
                                 const float* __restrict__ s2, const float* __restrict__ s3,
                                 const float* __restrict__ s4, const float* __restrict__ s5,
                                 const float* __restrict__ s6, const float* __restrict__ s7,
                                 float* __restrict__ ws) {
    __shared__ float tile[64][65];
    const float* srcs[8] = {s0, s1, s2, s3, s4, s5, s6, s7};
    const float* src = srcs[blockIdx.z];
    float* dst = ws + (size_t)blockIdx.z * (G4 * HH);
    int gblk = blockIdx.x * 64;
    int kblk = blockIdx.y * 64;
    for (int q = threadIdx.x; q < 64 * 64; q += 256) {
        int r = q >> 6, c = q & 63;
        tile[r][c] = src[(size_t)(gblk + r) * HH + (kblk + c)];
    }
    __syncthreads();
    for (int q = threadIdx.x; q < 64 * 64; q += 256) {
        int r = q & 3;
        int gl = (q >> 2) & 63;
        int k0l = q >> 8;
        int dsti = (((kblk >> 2) + k0l) * G4 + gblk + gl) * 4 + r;
        dst[dsti] = tile[gl][k0l * 4 + r];
    }
}

// dst[k*256+j] = src[j*256+k]
__global__ void transpose256_k(const float* __restrict__ W1, const float* __restrict__ W2,
                               float* __restrict__ ws) {
    __shared__ float tile[32][33];
    const float* src = blockIdx.z ? W2 : W1;
    float* dst = ws + (blockIdx.z ? W2T_OFF : W1T_OFF);
    int j0 = blockIdx.x * 32, k0 = blockIdx.y * 32;
    int tx = threadIdx.x & 31, ty = threadIdx.x >> 5;
    for (int i = ty; i < 32; i += 8) tile[i][tx] = src[(size_t)(j0 + i) * HH + k0 + tx];
    __syncthreads();
    for (int i = ty; i < 32; i += 8) dst[(size_t)(k0 + i) * HH + j0 + tx] = tile[tx][i];
}

__global__ void __launch_bounds__(NT) ptrnet_k(
    const float* __restrict__ inputs, const float* __restrict__ W_emb,
    const float* __restrict__ b_emb,
    const float* __restrict__ b_e0, const float* __restrict__ b_e1,
    const float* __restrict__ b_d0, const float* __restrict__ b_d1,
    const float* __restrict__ vv,
    float* __restrict__ ws, float* __restrict__ out, int useX1B) {
  const int g = blockIdx.x;
  const int role = g & 3;   // A/B/C/D; %8 striping -> each XCD hosts one role
  const int b = g >> 2;
  const int tid = threadIdx.x;

  const float4* ws4 = (const float4*)ws;
  const float4* We0ih = ws4 + 0*65536;
  const float4* We0hh = ws4 + 1*65536;
  const float4* We1ih = ws4 + 2*65536;
  const float4* We1hh = ws4 + 3*65536;
  const float4* Wd0ih = ws4 + 4*65536;
  const float4* Wd0hh = ws4 + 5*65536;
  const float4* Wd1ih = ws4 + 6*65536;
  const float4* Wd1hh = ws4 + 7*65536;
  const float* W1T = ws + W1T_OFF;
  const float* W2T = ws + W2T_OFF;

  float* pb   = ws + PB_OFF + (size_t)b * PBB;
  float* X1   = pb + OX1;    // A-private
  float* h1cw = pb + OH1;    // A -> B
  float* p2cw = pb + OP2;    // B -> C, ring 16
  float* h2cw = pb + OH2;    // C -> D
  float* dc1i = pb + ODC1;   // A -> D (pass-0 finals)
  float* dc2i = pb + ODC2;   // C -> D
  float* X1B  = ws + X1B_OFF + (size_t)b * 65536;  // A-private (guarded)
  unsigned* Wf  = (unsigned*)(ws + FLG_OFF);
  unsigned* flg = Wf + b*256;   // padded: each flag its own 128B line
  unsigned* abw = Wf + 32*256;

  __shared__ float big0[16384];  // A: preE->c1c; C: c2c; D: preE
  __shared__ float big1[16384];  // A: init staging; D: eW1
  __shared__ float gbuf[1024];
  __shared__ float v0[256], v1[256], v2[256], v3[256], v4[256], v5[256], v6[256];
  __shared__ float scr[64];
  __shared__ int msk[64];
  __shared__ int ibc[2];

  // ================= role A: layer-1 recurrence =================
  if (role == 0) {
    for (int i = tid; i < SS*HH; i += NT){
      int t = i >> 8, j = i & 255;
      const float* xr = inputs + ((size_t)b*SS + t)*8;
      float acc = b_emb[j];
#pragma unroll
      for (int d = 0; d < 8; ++d) acc = fmaf(xr[d], W_emb[j*8+d], acc);
      big0[i] = acc;  // preE
    }
    __syncthreads();
    // X1 (+X1alt) init: 16 tiles of 4 t, one weight stream serves both variants
    for (int tile = 0; tile < 16; ++tile){
      { int tt = tid >> 8, j = tid & 255;
        float pe = big0[(tile*4+tt)*256 + j];
        gbuf[tid] = tanhf(pe);
        big1[tid] = tanhf(pe + W_emb[j*8 + 7]); }
      __syncthreads();
      float a0=0.f,a1=0.f,a2=0.f,a3=0.f;
      float c0=0.f,c1=0.f,c2=0.f,c3=0.f;
      for (int kq = 0; kq < 64; ++kq){
        float4 w = We0ih[(kq<<10) + tid];
        a0 += dot4(w, *(const float4*)&gbuf[   0 + kq*4]);
        a1 += dot4(w, *(const float4*)&gbuf[ 256 + kq*4]);
        a2 += dot4(w, *(const float4*)&gbuf[ 512 + kq*4]);
        a3 += dot4(w, *(const float4*)&gbuf[ 768 + kq*4]);
        c0 += dot4(w, *(const float4*)&big1[   0 + kq*4]);
        c1 += dot4(w, *(const float4*)&big1[ 256 + kq*4]);
        c2 += dot4(w, *(const float4*)&big1[ 512 + kq*4]);
        c3 += dot4(w, *(const float4*)&big1[ 768 + kq*4]);
      }
      float bg = b_e0[tid];
      X1[(tile*4+0)*1024 + tid] = bg + a0;
      X1[(tile*4+1)*1024 + tid] = bg + a1;
      X1[(tile*4+2)*1024 + tid] = bg + a2;
      X1[(tile*4+3)*1024 + tid] = bg + a3;
      if (useX1B){
        X1B[(tile*4+0)*1024 + tid] = bg + c0;
        X1B[(tile*4+1)*1024 + tid] = bg + c1;
        X1B[(tile*4+2)*1024 + tid] = bg + c2;
        X1B[(tile*4+3)*1024 + tid] = bg + c3;
      }
      __syncthreads();
    }
    // big0 becomes c1c from here
    if (tid < 256) v0[tid] = 0.f;  // h1
    __syncthreads();
    int tau = 0;
    for (int p = 0; p < SS; ++p){
      int t0 = 0;
      float xr0 = 0.f;
      if (p > 0){
        if (tid == 0){
          int iv = wait_ge(&flg[FD], (unsigned)p << 8, abw);
          ibc[0] = (iv < 0) ? 0 : (iv & 255);
        }
        __syncthreads();
        t0 = ibc[0];
        if (useX1B){
          xr0 = X1B[t0*1024 + tid];     // precomputed flagged row
        } else {
          if (tid < 256){               // fallback: recompute embt + GEMV
            const float* xr = inputs + ((size_t)b*SS + t0)*8;
            float pe = b_emb[tid];
#pragma unroll
            for (int d = 0; d < 8; ++d) pe = fmaf(xr[d], W_emb[tid*8+d], pe);
            v1[tid] = tanhf(pe + W_emb[tid*8 + 7]);
          }
          __syncthreads();
          float accR = 0.f;
          for (int kq = 0; kq < 64; ++kq)
            accR += dot4(We0ih[(kq<<10) + tid], *(const float4*)&v1[kq*4]);
          xr0 = b_e0[tid] + accR;
        }
        X1[t0*1024 + tid] = xr0;        // permanent (cur flags accumulate)
        if (tid < 256) v0[tid] = (t0 > 0) ? lrel(&h1cw[(t0-1)*256 + tid]) : 0.f;
        __syncthreads();
      }
      for (int t = t0; t < SS; ++t){
        ++tau;
        float xv = (p > 0 && t == t0) ? xr0 : X1[t*1024 + tid];  // load in flight during GEMV
        float acc = 0.f;
        for (int kq = 0; kq < 64; ++kq)
          acc += dot4(We0hh[(kq<<10) + tid], *(const float4*)&v0[kq*4]);
        gbuf[tid] = acc + xv;
        __syncthreads();
        if (tid < 256){
          float Gi = gbuf[tid], Gf = gbuf[tid+256], Gg = gbuf[tid+512], Go = gbuf[tid+768];
          float cp = (t == 0) ? 0.f : big0[(t-1)*256 + tid];
          float cc = sigmf(Gf)*cp + sigmf(Gi)*tanhf(Gg);
          float hh = sigmf(Go)*tanhf(cc);
          big0[t*256 + tid] = cc; v0[tid] = hh;
          srel(&h1cw[t*256 + tid], hh);
          if (p == 0 && t == SS-1) srel(&dc1i[tid], cc);
        }
        drain_vm();
        __syncthreads();
        if (tid == 0) fst(&flg[FA], (unsigned)tau);
      }
    }
  }
  // ================= role B: p2(t) = b_e1 + Wih1 . h1(t) =================
  else if (role == 1) {
    int tau = 0;
    for (int p = 0; p < SS; ++p){
      int t0 = 0;
      if (p > 0){
        if (tid == 0){
          int iv = wait_ge(&flg[FD], (unsigned)p << 8, abw);
          ibc[0] = (iv < 0) ? 0 : (iv & 255);
        }
        __syncthreads();
        t0 = ibc[0];
      }
      for (int t = t0; t < SS; ++t){
        ++tau;
        if (tid == 0){
          wait_ge(&flg[FA], (unsigned)tau, abw);                       // progA
          if (tau > 16) wait_ge(&flg[FC], (unsigned)(tau-16), abw);    // ring backpressure
        }
        __syncthreads();
        if (tid < 256) v0[tid] = lrel(&h1cw[t*256 + tid]);
        __syncthreads();
        float acc = b_e1[tid];
        for (int kq = 0; kq < 64; ++kq)
          acc += dot4(We1ih[(kq<<10) + tid], *(const float4*)&v0[kq*4]);
        srel(&p2cw[(tau & 15)*1024 + tid], acc);
        drain_vm();
        __syncthreads();
        if (tid == 0) fst(&flg[FB], (unsigned)tau);
      }
    }
  }
  // ================= role C: layer-2 recurrence =================
  else if (role == 2) {
    int tau = 0;
    for (int p = 0; p < SS; ++p){
      int t0 = 0;
      if (p > 0){
        if (tid == 0){
          int iv = wait_ge(&flg[FD], (unsigned)p << 8, abw);
          ibc[0] = (iv < 0) ? 0 : (iv & 255);
        }
        __syncthreads();
        t0 = ibc[0];
      }
      if (tid < 256) v0[tid] = (t0 > 0) ? lrel(&h2cw[(t0-1)*256 + tid]) : 0.f;
      __syncthreads();
      for (int t = t0; t < SS; ++t){
        ++tau;
        if (tid == 0) wait_ge(&flg[FB], (unsigned)tau, abw);
        __syncthreads();
        float p2v = lrel(&p2cw[(tau & 15)*1024 + tid]);  // in flight during GEMV
        float acc = 0.f;
        for (int kq = 0; kq < 64; ++kq)
          acc += dot4(We1hh[(kq<<10) + tid], *(const float4*)&v0[kq*4]);
        gbuf[tid] = acc + p2v;
        __syncthreads();
        if (tid < 256){
          float Gi = gbuf[tid], Gf = gbuf[tid+256], Gg = gbuf[tid+512], Go = gbuf[tid+768];
          float cp = (t == 0) ? 0.f : big0[(t-1)*256 + tid];   // c2c
          float cc = sigmf(Gf)*cp + sigmf(Gi)*tanhf(Gg);
          float hh = sigmf(Go)*tanhf(cc);
          big0[t*256 + tid] = cc; v0[tid] = hh;
          srel(&h2cw[t*256 + tid], hh);
          if (p == 0 && t == SS-1) srel(&dc2i[tid], cc);
        }
        drain_vm();
        __syncthreads();
        if (tid == 0) fst(&flg[FC], (unsigned)tau);
      }
    }
  }
  // ================= role D: eW1, decoder cell, attention, argmax =================
  else {
    for (int i = tid; i < SS*HH; i += NT){
      int t = i >> 8, j = i & 255;
      const float* xr = inputs + ((size_t)b*SS + t)*8;
      float acc = b_emb[j];
#pragma unroll
      for (int d = 0; d < 8; ++d) acc = fmaf(xr[d], W_emb[j*8+d], acc);
      big0[i] = acc;  // preE, kept whole run
    }
    if (tid < 64) msk[tid] = 0;
    __syncthreads();

    // v2=dins v3=dh1 v4=dc1 v5=dh2 v6=dc2 v1=a2
    auto dec_cell = [&](){
      { float acc = b_d0[tid];
        for (int kq = 0; kq < 64; ++kq){
          acc += dot4(Wd0ih[(kq<<10) + tid], *(const float4*)&v2[kq*4]);
          acc += dot4(Wd0hh[(kq<<10) + tid], *(const float4*)&v3[kq*4]);
        }
        gbuf[tid] = acc; }
      __syncthreads();
      if (tid < 256){
        float Gi = gbuf[tid], Gf = gbuf[tid+256], Gg = gbuf[tid+512], Go = gbuf[tid+768];
        float cc = sigmf(Gf)*v4[tid] + sigmf(Gi)*tanhf(Gg);
        float hh = sigmf(Go)*tanhf(cc);
        v4[tid] = cc; v3[tid] = hh;
      }
      __syncthreads();
      { float acc = b_d1[tid];
        for (int kq = 0; kq < 64; ++kq){
          acc += dot4(Wd1ih[(kq<<10) + tid], *(const float4*)&v3[kq*4]);
          acc += dot4(Wd1hh[(kq<<10) + tid], *(const float4*)&v5[kq*4]);
        }
        gbuf[tid] = acc; }
      __syncthreads();
      if (tid < 256){
        float Gi = gbuf[tid], Gf = gbuf[tid+256], Gg = gbuf[tid+512], Go = gbuf[tid+768];
        float cc = sigmf(Gf)*v6[tid] + sigmf(Gi)*tanhf(Gg);
        float hh = sigmf(Go)*tanhf(cc);
        v6[tid] = cc; v5[tid] = hh;
      }
      __syncthreads();
      { int j = tid & 255, c = tid >> 8;   // a2 = dh2 @ W2^T
        float a = 0.f;
        for (int k = c*64; k < c*64 + 64; ++k) a = fmaf(v5[k], W2T[k*256 + j], a);
        gbuf[tid] = a; }
      __syncthreads();
      if (tid < 256) v1[tid] = gbuf[tid] + gbuf[tid+256] + gbuf[tid+512] + gbuf[tid+768];
      __syncthreads();
    };

    int tau = 0, lastidx = 0;
    for (int p = 0; p < SS; ++p){
      int t0 = (p == 0) ? 0 : lastidx;
      if (p > 0) dec_cell();   // overlaps with upstream re-encode
      for (int t = t0; t < SS; ++t){
        ++tau;
        if (tid == 0) wait_ge(&flg[FC], (unsigned)tau, abw);
        __syncthreads();
        if (tid < 256) v0[tid] = lrel(&h2cw[t*256 + tid]);
        __syncthreads();
        { int j = tid & 255, c = tid >> 8;   // eW1 row t
          float a = 0.f;
          for (int k = c*64; k < c*64 + 64; ++k) a = fmaf(v0[k], W1T[k*256 + j], a);
          gbuf[tid] = a; }
        __syncthreads();
        if (tid < 256) big1[t*256 + tid] = gbuf[tid] + gbuf[tid+256] + gbuf[tid+512] + gbuf[tid+768];
        __syncthreads();
      }
      if (p == 0){
        if (tid < 256){
          v3[tid] = lrel(&h1cw[63*256 + tid]);
          v4[tid] = lrel(&dc1i[tid]);
          v5[tid] = lrel(&h2cw[63*256 + tid]);
          v6[tid] = lrel(&dc2i[tid]);
          v2[tid] = lrel(&h2cw[0*256 + tid]);
        }
        __syncthreads();
        dec_cell();
      }
      // scores: 16 lanes per t
      { int t = tid >> 4, r = tid & 15;
        float a = 0.f;
        for (int j = r; j < HH; j += 16) a += vv[j] * tanhf(big1[t*256 + j] + v1[j]);
        a += __shfl_xor(a, 8, 16);
        a += __shfl_xor(a, 4, 16);
        a += __shfl_xor(a, 2, 16);
        a += __shfl_xor(a, 1, 16);
        if (r == 0) scr[t] = msk[t] ? -3.0e38f : a; }
      __syncthreads();
      if (tid < SS){
        float sv = scr[tid];
        float m = sv; int mi = tid;
#pragma unroll
        for (int o = 32; o >= 1; o >>= 1){
          float ov = __shfl_xor(m, o, 64);
          int oi = __shfl_xor(mi, o, 64);
          if (ov > m || (ov == m && oi < mi)){ m = ov; mi = oi; }
        }
        float e = expf(sv - m);
        float ssum = e;
#pragma unroll
        for (int o = 32; o >= 1; o >>= 1) ssum += __shfl_xor(ssum, o, 64);
        out[((size_t)b*SS + p)*SS + tid] = e / ssum;
        if (tid == 0){
          msk[mi] = 1;
          out[(size_t)BB*SS*SS + (size_t)b*SS + p] = (float)mi;
          ibc[1] = mi;
        }
      }
      __syncthreads();
      int idx = ibc[1];
      lastidx = idx;
      if (p < SS-1){
        if (tid < 256) v2[tid] = lrel(&h2cw[idx*256 + tid]);  // dins, read BEFORE publish
        drain_vm();
        __syncthreads();
        if (tid == 0) fst(&flg[FD], ((unsigned)(p+1) << 8) | (unsigned)idx);
      }
    }
  }
}

extern "C" void kernel_launch(void* const* d_in, const int* in_sizes, int n_in,
                              void* d_out, int out_size, void* d_ws, size_t ws_size,
                              hipStream_t stream) {
  const float* inputs = (const float*)d_in[0];
  const float* W_emb  = (const float*)d_in[1];
  const float* b_emb  = (const float*)d_in[2];
  const float* e_Wih0 = (const float*)d_in[3];
  const float* e_Whh0 = (const float*)d_in[4];
  const float* e_b0   = (const float*)d_in[5];
  const float* e_Wih1 = (const float*)d_in[6];
  const float* e_Whh1 = (const float*)d_in[7];
  const float* e_b1   = (const float*)d_in[8];
  const float* d_Wih0 = (const float*)d_in[9];
  const float* d_Whh0 = (const float*)d_in[10];
  const float* d_b0   = (const float*)d_in[11];
  const float* d_Wih1 = (const float*)d_in[12];
  const float* d_Whh1 = (const float*)d_in[13];
  const float* d_b1   = (const float*)d_in[14];
  const float* W1     = (const float*)d_in[15];
  const float* W2     = (const float*)d_in[16];
  const float* v      = (const float*)d_in[17];
  float* ws  = (float*)d_ws;
  float* out = (float*)d_out;

  size_t need = ((size_t)X1B_OFF + 32u*65536u) * 4u;
  int useX1B = (ws_size >= need) ? 1 : 0;

  zflags_k<<<dim3(9), dim3(1024), 0, stream>>>(ws);
  pack_transpose_k<<<dim3(16, 4, 8), dim3(256), 0, stream>>>(
      e_Wih0, e_Whh0, e_Wih1, e_Whh1, d_Wih0, d_Whh0, d_Wih1, d_Whh1, ws);
  transpose256_k<<<dim3(8, 8, 2), dim3(256), 0, stream>>>(W1, W2, ws);
  ptrnet_k<<<dim3(BB*4), dim3(NT), 0, stream>>>(
      inputs, W_emb, b_emb, e_b0, e_b1, d_b0, d_b1, v, ws, out, useX1B);
}